// Round 9
// baseline (54.340 us; speedup 1.0000x reference)
//
#include <hip/hip_runtime.h>
#include <math.h>

#define TT 1024
#define DD 128

static constexpr float kNegInf = -1e9f;

typedef __fp16 h2 __attribute__((ext_vector_type(2)));

__device__ __forceinline__ unsigned int pk16(float a, float b) {
  h2 v = __builtin_amdgcn_cvt_pkrtz(a, b);
  return __builtin_bit_cast(unsigned int, v);
}
__device__ __forceinline__ float dot2f(unsigned int a, unsigned int b, float c) {
#if __has_builtin(__builtin_amdgcn_fdot2)
  return __builtin_amdgcn_fdot2(__builtin_bit_cast(h2, a),
                                __builtin_bit_cast(h2, b), c, false);
#else
  h2 av = __builtin_bit_cast(h2, a), bv = __builtin_bit_cast(h2, b);
  return c + (float)av.x * (float)bv.x + (float)av.y * (float)bv.y;
#endif
}

// ---- K0: full transpose f32 [d][j], f16 j-pair pack [jp][d], swj/bias ----
// 64 blocks, tile = 32 j-rows.
__global__ __launch_bounds__(256) void k_prep(const float* __restrict__ h,
                                              const float* __restrict__ w,
                                              const int* __restrict__ mk,
                                              float* __restrict__ hTf,
                                              unsigned int* __restrict__ hT16,
                                              float* __restrict__ swj,
                                              float* __restrict__ bias) {
  __shared__ __align__(16) float tile[32][132];
  __shared__ float wred[32][8];
  const int b  = blockIdx.x >> 5;
  const int jt = blockIdx.x & 31;
  const int tid = threadIdx.x;
  const float4* src = (const float4*)h + (size_t)(b * TT + jt * 32) * 32;
#pragma unroll
  for (int k = 0; k < 4; ++k) {
    int idx = k * 256 + tid;             // 0..1023
    float4 v = src[idx];
    int j = idx >> 5, c = idx & 31;
    *((float4*)&tile[j][c * 4]) = v;
  }
  __syncthreads();
  // hTf[d][j]: 128 d x 32 j = 1024 float4 writes
#pragma unroll
  for (int k = 0; k < 4; ++k) {
    int idx = k * 256 + tid;             // 0..1023
    int d = idx >> 3, jq = idx & 7;
    float4 v = {tile[jq * 4 + 0][d], tile[jq * 4 + 1][d],
                tile[jq * 4 + 2][d], tile[jq * 4 + 3][d]};
    *(float4*)&hTf[(size_t)(b * DD + d) * TT + jt * 32 + jq * 4] = v;
  }
  // hT16[jp][d]: 16 jp x 128 d words = 512 uint4 writes
#pragma unroll
  for (int k = 0; k < 2; ++k) {
    int idx = k * 256 + tid;             // 0..511
    int jp = idx >> 5, dq = idx & 31;
    uint4 wv;
    wv.x = pk16(tile[jp * 2][dq * 4 + 0], tile[jp * 2 + 1][dq * 4 + 0]);
    wv.y = pk16(tile[jp * 2][dq * 4 + 1], tile[jp * 2 + 1][dq * 4 + 1]);
    wv.z = pk16(tile[jp * 2][dq * 4 + 2], tile[jp * 2 + 1][dq * 4 + 2]);
    wv.w = pk16(tile[jp * 2][dq * 4 + 3], tile[jp * 2 + 1][dq * 4 + 3]);
    *(uint4*)&hT16[((size_t)(b * 512 + jt * 16 + jp)) * DD + dq * 4] = wv;
  }
  // wj partial: thread = (row j 0..31, dim-eighth dg 0..7)
  {
    const int j = tid & 31, dg = tid >> 5;
    float p = 0.f;
#pragma unroll
    for (int e = 0; e < 16; e += 4) {
      float4 hv = *(const float4*)&tile[j][dg * 16 + e];
      float4 wv = *(const float4*)&w[dg * 16 + e];
      p += hv.x * wv.x + hv.y * wv.y + hv.z * wv.z + hv.w * wv.w;
    }
    wred[j][dg] = p;
  }
  __syncthreads();
  if (tid < 32) {
    const int row = b * TT + jt * 32 + tid;
    float a = 0.f;
#pragma unroll
    for (int e = 0; e < 8; ++e) a += wred[tid][e];
    const bool ok = (mk[row] != 0);
    swj[row]  = ok ? -a : 0.f;
    bias[row] = ok ? 0.f : kNegInf;
  }
}

// ---- K1: 8 rows x 256 j per block; 256 rowgroups x 4 j-splits = 1024 blocks.
// wave = 2 rows x full 256-j slice (J=4 per lane).
__global__ __launch_bounds__(256, 4) void k_fused(
    const float* __restrict__ h, const float* __restrict__ hTf,
    const unsigned int* __restrict__ hT16,
    const float* __restrict__ swj, const float* __restrict__ bias,
    float* __restrict__ ctxpart, float2* __restrict__ mlpart) {
  __shared__ __align__(16) unsigned int Pt[128][8];   // 4 KB [jp_local][row]
  __shared__ __align__(16) float ctxp[4][8][DD];      // 16 KB [g][row][d]

  const int tid  = threadIdx.x;
  const int rg   = blockIdx.x & 255;          // rowgroup (8 rows), spans batches
  const int js   = blockIdx.x >> 8;           // j-split 0..3
  const int b    = rg >> 7;
  const int lane = tid & 63;
  const int wv   = tid >> 6;                  // wave id 0..3
  const int urow = __builtin_amdgcn_readfirstlane((rg & 127) * 8 + wv * 2);
  const float* hA0 = h + ((size_t)b * TT + urow) * DD;   // wave-uniform
  const float* hA1 = hA0 + DD;
  const int jv = js * 256 + lane * 4;         // this lane's j quad
  const float* hjb = hTf + (size_t)b * DD * TT;

  // ---------------- phase 1: distances, J=4 x R=2 ----------------
  float a00 = 0.f, a01 = 0.f, a02 = 0.f, a03 = 0.f;
  float a10 = 0.f, a11 = 0.f, a12 = 0.f, a13 = 0.f;
#pragma unroll 2
  for (int c = 0; c < 16; ++c) {              // 8 dims per chunk
    float a0v[8], a1v[8];
    {
      float4 t0 = *(const float4*)(hA0 + c * 8);
      float4 t1 = *(const float4*)(hA0 + c * 8 + 4);
      a0v[0] = t0.x; a0v[1] = t0.y; a0v[2] = t0.z; a0v[3] = t0.w;
      a0v[4] = t1.x; a0v[5] = t1.y; a0v[6] = t1.z; a0v[7] = t1.w;
      float4 t2 = *(const float4*)(hA1 + c * 8);
      float4 t3 = *(const float4*)(hA1 + c * 8 + 4);
      a1v[0] = t2.x; a1v[1] = t2.y; a1v[2] = t2.z; a1v[3] = t2.w;
      a1v[4] = t3.x; a1v[5] = t3.y; a1v[6] = t3.z; a1v[7] = t3.w;
    }
#pragma unroll
    for (int e = 0; e < 8; ++e) {
      const float4 Bv = *(const float4*)(hjb + (size_t)(c * 8 + e) * TT + jv);
      a00 += fabsf(a0v[e] - Bv.x); a01 += fabsf(a0v[e] - Bv.y);
      a02 += fabsf(a0v[e] - Bv.z); a03 += fabsf(a0v[e] - Bv.w);
      a10 += fabsf(a1v[e] - Bv.x); a11 += fabsf(a1v[e] - Bv.y);
      a12 += fabsf(a1v[e] - Bv.z); a13 += fabsf(a1v[e] - Bv.w);
    }
  }

  // ---------------- softmax: pure wave-local ----------------
  const float4 swv = *(const float4*)(swj + (size_t)b * TT + jv);
  const float4 bvv = *(const float4*)(bias + (size_t)b * TT + jv);
  float sc0[4], sc1[4];
  sc0[0] = fmaf(swv.x, a00, bvv.x); sc0[1] = fmaf(swv.y, a01, bvv.y);
  sc0[2] = fmaf(swv.z, a02, bvv.z); sc0[3] = fmaf(swv.w, a03, bvv.w);
  sc1[0] = fmaf(swv.x, a10, bvv.x); sc1[1] = fmaf(swv.y, a11, bvv.y);
  sc1[2] = fmaf(swv.z, a12, bvv.z); sc1[3] = fmaf(swv.w, a13, bvv.w);

  float m0 = fmaxf(fmaxf(sc0[0], sc0[1]), fmaxf(sc0[2], sc0[3]));
  float m1 = fmaxf(fmaxf(sc1[0], sc1[1]), fmaxf(sc1[2], sc1[3]));
#pragma unroll
  for (int off = 32; off; off >>= 1) {
    m0 = fmaxf(m0, __shfl_xor(m0, off));
    m1 = fmaxf(m1, __shfl_xor(m1, off));
  }
  float p0[4], p1[4];
#pragma unroll
  for (int u = 0; u < 4; ++u) {
    p0[u] = __expf(sc0[u] - m0);
    p1[u] = __expf(sc1[u] - m1);
  }
  float l0 = (p0[0] + p0[1]) + (p0[2] + p0[3]);
  float l1 = (p1[0] + p1[1]) + (p1[2] + p1[3]);
#pragma unroll
  for (int off = 32; off; off >>= 1) {
    l0 += __shfl_xor(l0, off);
    l1 += __shfl_xor(l1, off);
  }
  // P words: [jp_local][row]
  Pt[lane * 2 + 0][wv * 2 + 0] = pk16(p0[0], p0[1]);
  Pt[lane * 2 + 1][wv * 2 + 0] = pk16(p0[2], p0[3]);
  Pt[lane * 2 + 0][wv * 2 + 1] = pk16(p1[0], p1[1]);
  Pt[lane * 2 + 1][wv * 2 + 1] = pk16(p1[2], p1[3]);
  if (lane == 0) {
    mlpart[js * 2048 + rg * 8 + wv * 2 + 0] = make_float2(m0, l0);
    mlpart[js * 2048 + rg * 8 + wv * 2 + 1] = make_float2(m1, l1);
  }
  __syncthreads();

  // ---------------- PV via dot2: thread = (dpair 64) x (g 4) ----------------
  const int dp = tid & 63;
  const int g  = __builtin_amdgcn_readfirstlane(tid >> 6);   // 32 jp each
  const unsigned int* Vp =
      hT16 + ((size_t)(b * 512 + js * 128 + g * 32)) * DD + dp * 2;
  float cx[8][2];
#pragma unroll
  for (int r = 0; r < 8; ++r) { cx[r][0] = 0.f; cx[r][1] = 0.f; }
#pragma unroll 4
  for (int t = 0; t < 32; ++t) {
    const uint4 Pa = *(const uint4*)&Pt[g * 32 + t][0];
    const uint4 Pb = *(const uint4*)&Pt[g * 32 + t][4];
    const uint2 V  = *(const uint2*)(Vp + (size_t)t * DD);
    cx[0][0] = dot2f(Pa.x, V.x, cx[0][0]); cx[0][1] = dot2f(Pa.x, V.y, cx[0][1]);
    cx[1][0] = dot2f(Pa.y, V.x, cx[1][0]); cx[1][1] = dot2f(Pa.y, V.y, cx[1][1]);
    cx[2][0] = dot2f(Pa.z, V.x, cx[2][0]); cx[2][1] = dot2f(Pa.z, V.y, cx[2][1]);
    cx[3][0] = dot2f(Pa.w, V.x, cx[3][0]); cx[3][1] = dot2f(Pa.w, V.y, cx[3][1]);
    cx[4][0] = dot2f(Pb.x, V.x, cx[4][0]); cx[4][1] = dot2f(Pb.x, V.y, cx[4][1]);
    cx[5][0] = dot2f(Pb.y, V.x, cx[5][0]); cx[5][1] = dot2f(Pb.y, V.y, cx[5][1]);
    cx[6][0] = dot2f(Pb.z, V.x, cx[6][0]); cx[6][1] = dot2f(Pb.z, V.y, cx[6][1]);
    cx[7][0] = dot2f(Pb.w, V.x, cx[7][0]); cx[7][1] = dot2f(Pb.w, V.y, cx[7][1]);
  }
#pragma unroll
  for (int r = 0; r < 8; ++r) {
    float2 cv = {cx[r][0], cx[r][1]};
    *(float2*)&ctxp[g][r][dp * 2] = cv;
  }
  __syncthreads();

  // final: reduce 4 g-slices, write ctx partial
#pragma unroll
  for (int k = 0; k < 4; ++k) {
    const int idx = tid + k * 256;           // 0..1023
    const int r = idx >> 7, d = idx & 127;
    ctxpart[((size_t)(js * 2048 + rg * 8 + r)) * DD + d] =
        (ctxp[0][r][d] + ctxp[1][r][d]) + (ctxp[2][r][d] + ctxp[3][r][d]);
  }
}

// ---- K2: merge 4 j-split partials, normalize, write concat(h, ctx) ----
__global__ __launch_bounds__(256) void k_merge(const float* __restrict__ h,
                                               const float* __restrict__ ctxpart,
                                               const float2* __restrict__ mlpart,
                                               float* __restrict__ out) {
  const int row = blockIdx.x * 2 + (threadIdx.x >> 7);   // 0..2047
  const int d   = threadIdx.x & 127;

  float mg[4], lg[4];
#pragma unroll
  for (int g = 0; g < 4; ++g) {
    const float2 ml = mlpart[g * 2048 + row];
    mg[g] = ml.x; lg[g] = ml.y;
  }
  const float M = fmaxf(fmaxf(mg[0], mg[1]), fmaxf(mg[2], mg[3]));
  float L = 0.f, c = 0.f;
#pragma unroll
  for (int g = 0; g < 4; ++g) {
    const float wg = __expf(mg[g] - M);
    L = fmaf(lg[g], wg, L);
    c = fmaf(ctxpart[((size_t)(g * 2048 + row)) * DD + d], wg, c);
  }
  out[(size_t)row * 256 + d]       = h[(size_t)row * DD + d];
  out[(size_t)row * 256 + 128 + d] = c / L;
}

extern "C" void kernel_launch(void* const* d_in, const int* in_sizes, int n_in,
                              void* d_out, int out_size, void* d_ws, size_t ws_size,
                              hipStream_t stream) {
  const float* h  = (const float*)d_in[0];
  const int*   mk = (const int*)d_in[1];
  const float* w  = (const float*)d_in[2];
  float* out = (float*)d_out;

  char* ws = (char*)d_ws;
  float*        swj  = (float*)ws;                                   // 8 KB
  float*        bias = (float*)(ws + 8192);                          // 8 KB
  float*        hTf  = (float*)(ws + 16384);                         // 1 MB
  unsigned int* hT16 = (unsigned int*)(ws + 16384 + 1048576);        // 512 KB
  float*  ctxpart = (float*)(ws + 16384 + 1048576 + 524288);         // 4 MB
  float2* mlpart  = (float2*)(ws + 16384 + 1048576 + 524288 + 4194304);  // 64 KB

  hipLaunchKernelGGL(k_prep,  dim3(64),   dim3(256), 0, stream,
                     h, w, mk, hTf, hT16, swj, bias);
  hipLaunchKernelGGL(k_fused, dim3(1024), dim3(256), 0, stream,
                     h, hTf, hT16, swj, bias, ctxpart, mlpart);
  hipLaunchKernelGGL(k_merge, dim3(1024), dim3(256), 0, stream,
                     h, ctxpart, mlpart, out);
}